// Round 9
// baseline (1144.101 us; speedup 1.0000x reference)
//
#include <hip/hip_runtime.h>
#include <hip/hip_cooperative_groups.h>
#include <stdint.h>

// RGCN round 9: cooperative mega-kernel, launch-size adaptive.
// r8 post-mortem: absmax == stub value -> output zeros -> cooperative launch
// was REJECTED (unchecked hipErrorCooperativeLaunchTooLarge): hand-computed
// 4 blocks/CU disagreed with the runtime's occupancy. Fix:
//   (1) grid = min(1024, occupancy_query * num_CUs)  (same arithmetic the
//       validator uses -> launch cannot be too large)
//   (2) every phase is a grid-stride loop over gridDim.x (r7-verbatim bodies)
//   (3) if the coop launch still errors, fall back to per-phase kernels
//       (== r7's proven 371 us path) so correctness is guaranteed.

namespace cg = cooperative_groups;

typedef float  f32x4  __attribute__((ext_vector_type(4)));
typedef __bf16 bf16x8 __attribute__((ext_vector_type(8)));
typedef __bf16 bf16x4 __attribute__((ext_vector_type(4)));
typedef unsigned short ushort8v __attribute__((ext_vector_type(8)));
typedef uint32_t uint4v __attribute__((ext_vector_type(4)));

#define MBATCH 32
#define ETYPES 4
#define NNODE  512
#define HIDD   128

#define GLB(p) (const __attribute__((address_space(1))) uint32_t*)(p)
#define LDSp(p) (__attribute__((address_space(3))) uint32_t*)(p)

// packed-weight pool offsets (elements)
#define WP_S0 0
#define WP_E0 8192
#define WP_S1 40960
#define WP_E1 57344
#define WP_S2 122880
#define WP_E2 139264
#define WP_W1 204800
#define WP_W2 221184

#define SMEM_BYTES 33792

struct Params {
  const float* x;
  const float* adj;
  const float* wself[3]; const float* bself[3];
  const float* wedge[3]; const float* bedge[3];
  const float* bng[3];   const float* bnb[3];
  const float* w1; const float* b1;
  const float* bnfg; const float* bnfb;
  const float* w2; const float* b2;
  __bf16* mmp; float* hs; float* part;
  __bf16* hb0; __bf16* hb1;
  uint32_t* bm; float* degp; __bf16* wp;
  float* out;
};

// ---------------- phase: pack (r7 body, grid-stride over 16384 row-groups) ----------------
__device__ void pack_phase(const float* __restrict__ adj, uint32_t* __restrict__ bm,
                           float* __restrict__ degp, int bid, int t, int nbl) {
  int wave = t >> 6, lane = t & 63;
  for (int rg = bid; rg < 16384; rg += nbl) {
    int r = rg * 4 + wave;                  // 65536 rows (b,e,n)
    int b = r >> 11, e = (r >> 9) & 3, n = r & 511;
    const float* row = adj + (long)r * 512;
    uint32_t myw = 0;
#pragma unroll
    for (int i = 0; i < 8; ++i) {
      uint64_t bal = __ballot(row[i * 64 + lane] != 0.f);
      uint32_t lo = (uint32_t)bal, hi = (uint32_t)(bal >> 32);
      if ((lane >> 1) == i) myw = (lane & 1) ? hi : lo;
    }
    if (lane == (n >> 5)) myw &= ~(1u << (n & 31));   // zero diagonal
    int pc = (lane < 16) ? __popc(myw) : 0;
    pc += __shfl_down(pc, 8);
    pc += __shfl_down(pc, 4);
    pc += __shfl_down(pc, 2);
    pc += __shfl_down(pc, 1);
    if (lane < 16) bm[(long)r * 16 + lane] = myw;
    if (lane == 0) degp[e * 16384 + b * 512 + n] = (float)pc;
  }
}

// ---------------- phase: prep (r7 body, grid-stride per weight mat) ----------------
__device__ void prep_phase(const Params& P, int bid, int t, int nbl) {
  const float* Ws[8] = {P.wself[0], P.wedge[0], P.wself[1], P.wedge[1],
                        P.wself[2], P.wedge[2], P.w1, P.w2};
  const int Kt[8]  = {64, 64, 128, 128, 128, 128, 128, 128};
  const int NB[8]  = {2, 8, 2, 8, 2, 8, 2, 2};
  const int OFF[8] = {WP_S0, WP_E0, WP_S1, WP_E1, WP_S2, WP_E2, WP_W1, WP_W2};
#pragma unroll
  for (int wid = 0; wid < 8; ++wid) {
    int K = Kt[wid], nblk = NB[wid];
    int tot = K * nblk * 64;
    for (int gid = bid * 256 + t; gid < tot; gid += nbl * 256) {
      int c = gid & 63;
      int k = (gid >> 6) % K;
      int blk = (gid >> 6) / K;
      int edge = (nblk == 8);
      int WS = edge ? 512 : 128;
      int col = edge ? (((blk & 1) * 64 + c) * 4 + (blk >> 1)) : (blk * 64 + c);
      P.wp[OFF[wid] + (long)blk * K * 64 + (k >> 3) * 512 + c * 8 + (k & 7)] =
          (__bf16)Ws[wid][k * WS + col];
    }
  }
}

// ---------------- phase: gemm (r7 body; iv from degp inline; grid-stride) ----------------
template <int K, bool F32IN>
__device__ void gemm_phase(char* smem, const void* __restrict__ hv,
                           const __bf16* __restrict__ wp_self,
                           const float* __restrict__ bias_self,
                           const __bf16* __restrict__ wp_edge,
                           const float* __restrict__ bias_edge,
                           const float* __restrict__ degp,
                           float* __restrict__ outF, __bf16* __restrict__ mmp,
                           int ntiles, int bid, int t, int nbl) {
  __bf16 (*Hl)[K + 8] = (__bf16(*)[K + 8])smem;
  __bf16* Wl = (__bf16*)(smem + 64 * (K + 8) * 2);   // k-packed [K/8][64][8]
  int wave = t >> 6, lane = t & 63, l15 = lane & 15, q = lane >> 4;
  for (int tile = bid; tile < ntiles; tile += nbl) {
    __syncthreads();                     // smem free from prev tile/phase
    int g0 = (tile & 255) * 64;
    int by = tile >> 8;
    bool edge = by >= 2;
    // stage W: contiguous K*128-byte copy via global_load_lds
    {
      const __bf16* wblk = edge ? (wp_edge + (long)(by - 2) * K * 64)
                                : (wp_self + (long)by * K * 64);
      const char* g = (const char*)wblk;
#pragma unroll
      for (int i = 0; i < K / 32; ++i) {
        __builtin_amdgcn_global_load_lds(GLB(g + i * 4096 + wave * 1024 + lane * 16),
                                         LDSp((char*)Wl + i * 4096 + wave * 1024),
                                         16, 0, 0);
      }
    }
    // stage H (coalesced, padded rows)
    for (int idx = t; idx < 64 * (K / 8); idx += 256) {
      int r = idx / (K / 8), ch = idx % (K / 8);
      if (F32IN) {
        const float* xf = (const float*)hv;
        f32x4 a = *(const f32x4*)(xf + (long)(g0 + r) * K + ch * 8);
        f32x4 bq = *(const f32x4*)(xf + (long)(g0 + r) * K + ch * 8 + 4);
        bf16x8 o;
#pragma unroll
        for (int j = 0; j < 4; ++j) { o[j] = (__bf16)a[j]; o[4 + j] = (__bf16)bq[j]; }
        *(bf16x8*)&Hl[r][ch * 8] = o;
      } else {
        const __bf16* hb = (const __bf16*)hv;
        *(bf16x8*)&Hl[r][ch * 8] = *(const bf16x8*)(hb + (long)(g0 + r) * K + ch * 8);
      }
    }
    __syncthreads();
    f32x4 acc[4] = {};
#pragma unroll
    for (int kk = 0; kk < K / 32; ++kk) {
      bf16x8 af = *(const bf16x8*)&Hl[wave * 16 + l15][kk * 32 + q * 8];
#pragma unroll
      for (int c = 0; c < 4; ++c) {
        bf16x8 bfr = *(const bf16x8*)&Wl[((kk * 4 + q) * 64 + c * 16 + l15) * 8];
        acc[c] = __builtin_amdgcn_mfma_f32_16x16x32_bf16(af, bfr, acc[c], 0, 0, 0);
      }
    }
    // D: row = q*4+i (within wave's 16-row tile), col = c*16+l15
    if (!edge) {
      int c0 = by * 64;
#pragma unroll
      for (int c = 0; c < 4; ++c) {
        float bc = bias_self[c0 + c * 16 + l15];
#pragma unroll
        for (int i = 0; i < 4; ++i) {
          int g = g0 + wave * 16 + q * 4 + i;
          outF[(long)g * HIDD + c0 + c * 16 + l15] = acc[c][i] + bc;
        }
      }
    } else {
      int blk = by - 2;
      int e = blk >> 1, o0 = (blk & 1) * 64;
      float iv[4];
#pragma unroll
      for (int i = 0; i < 4; ++i) {
        int gg = g0 + wave * 16 + q * 4 + i;
        float d = degp[gg] + degp[16384 + gg] + degp[32768 + gg] + degp[49152 + gg];
        iv[i] = d > 0.f ? 1.f / d : 0.f;       // bit-identical to r7 k_inv
      }
      int b4e  = (g0 >> 9) * 4 + e;
      int octg = ((g0 & 511) >> 3) + wave * 2 + (q >> 1);
      int j0   = (q & 1) * 4;
#pragma unroll
      for (int c = 0; c < 4; ++c) {
        int o = o0 + c * 16 + l15;
        float bc = bias_edge[o * 4 + e];
        bf16x4 v4;
#pragma unroll
        for (int i = 0; i < 4; ++i) v4[i] = (__bf16)((acc[c][i] + bc) * iv[i]);
        *(bf16x4*)(mmp + ((long)(b4e * 64 + octg) * HIDD + o) * 8 + j0) = v4;
      }
    }
  }
}

// ---------------- phase: spmm (r7 body verbatim, grid-stride over 1024 tiles) ----------------
__device__ void spmm_phase(char* smem, const uint32_t* __restrict__ bm,
                           const __bf16* __restrict__ mmp,
                           float* __restrict__ part, int bid, int t, int nbl) {
  __bf16* Bl = (__bf16*)smem;           // [oct(8)][o_local(64)][j(8)] = 8 KB
  int wave = t >> 6, lane = t & 63, l15 = lane & 15, q = lane >> 4;
  for (int tl = bid; tl < 1024; tl += nbl) {
    int tile = tl >> 7;                 // 0..7 = nt*2 + oc
    int eb   = tl & 127;                // e*32 + b
    int e = eb >> 5, b = eb & 31;
    int nt = tile >> 1, oc = tile & 1;
    int n0 = nt * 128, o0 = oc * 64;

    const uint32_t* bmr = bm + ((long)((b * 4 + e) * 512 + n0 + wave * 32 + l15)) * 16;
    uint32_t rm0[16], rm1[16];
#pragma unroll
    for (int i = 0; i < 4; ++i) {
      uint4v v0 = *(const uint4v*)(bmr + i * 4);
      uint4v v1 = *(const uint4v*)(bmr + 256 + i * 4);   // +16 rows * 16 words
      rm0[i * 4 + 0] = v0.x; rm0[i * 4 + 1] = v0.y; rm0[i * 4 + 2] = v0.z; rm0[i * 4 + 3] = v0.w;
      rm1[i * 4 + 0] = v1.x; rm1[i * 4 + 1] = v1.y; rm1[i * 4 + 2] = v1.z; rm1[i * 4 + 3] = v1.w;
    }

    f32x4 acc0[4] = {}, acc1[4] = {};
#pragma unroll 1
    for (int mc = 0; mc < 8; ++mc) {
      __syncthreads();   // Bl free from previous iter / tile / phase
#pragma unroll
      for (int i = 0; i < 2; ++i) {
        int oct = wave * 2 + i;
        const char* g = (const char*)mmp +
            ((long)(b * 4 + e) * 65536 + mc * 8192 + oct * 1024 + o0 * 8) * 2;
        __builtin_amdgcn_global_load_lds(GLB(g + lane * 16),
                                         LDSp((char*)Bl + oct * 1024),
                                         16, 0, 0);
      }
      __syncthreads();   // loads drained
#pragma unroll
      for (int kk = 0; kk < 2; ++kk) {
        uint32_t bits0 = (rm0[mc * 2 + kk] >> (q * 8)) & 0xffu;
        uint32_t bits1 = (rm1[mc * 2 + kk] >> (q * 8)) & 0xffu;
        ushort8v a0, a1;
#pragma unroll
        for (int j = 0; j < 8; ++j) {
          a0[j] = (bits0 >> j & 1u) ? (unsigned short)0x3F80 : (unsigned short)0;
          a1[j] = (bits1 >> j & 1u) ? (unsigned short)0x3F80 : (unsigned short)0;
        }
        union { ushort8v u; bf16x8 v; } c0, c1; c0.u = a0; c1.u = a1;
#pragma unroll
        for (int c = 0; c < 4; ++c) {
          bf16x8 bfr = *(const bf16x8*)&Bl[((kk * 4 + q) * 64 + c * 16 + l15) * 8];
          acc0[c] = __builtin_amdgcn_mfma_f32_16x16x32_bf16(c0.v, bfr, acc0[c], 0, 0, 0);
          acc1[c] = __builtin_amdgcn_mfma_f32_16x16x32_bf16(c1.v, bfr, acc1[c], 0, 0, 0);
        }
      }
    }
    float* dst = part + (long)(e * 32 + b) * NNODE * HIDD;
#pragma unroll
    for (int c = 0; c < 4; ++c) {
#pragma unroll
      for (int i = 0; i < 4; ++i) {
        int n = n0 + wave * 32 + q * 4 + i;
        int o = o0 + c * 16 + l15;
        dst[(long)n * HIDD + o] = acc0[c][i];
        dst[(long)(n + 16) * HIDD + o] = acc1[c][i];
      }
    }
  }
}

// ---------------- phase: bnstat (r7 body, grid-stride over 512 nodes) ----------------
template <bool HASP>
__device__ void bnstat_phase(char* smem, const float* __restrict__ hs,
                             const float* __restrict__ part,
                             const float* __restrict__ gg,
                             const float* __restrict__ bb,
                             __bf16* __restrict__ hb, int bid, int t, int nbl) {
  float* sm = (float*)smem;             // 4096 floats
  float* rs = (float*)(smem + 16384);   // 256
  float* rq = (float*)(smem + 17408);   // 256
  float* bc = (float*)(smem + 18432);   // 2
  int o4 = t & 31, bq = t >> 5;
  for (int n = bid; n < 512; n += nbl) {
    __syncthreads();                    // smem free from previous n / phase
    float s = 0.f, sq = 0.f;
#pragma unroll
    for (int i = 0; i < 4; ++i) {
      int b = bq + i * 8;
      long base = ((long)b * NNODE + n) * HIDD + o4 * 4;
      f32x4 v = *(const f32x4*)(hs + base);
      if (HASP) {
#pragma unroll
        for (int e = 0; e < 4; ++e)
          v += *(const f32x4*)(part + ((long)(e * 32 + b) * NNODE + n) * HIDD + o4 * 4);
      }
      *(f32x4*)&sm[b * 128 + o4 * 4] = v;
#pragma unroll
      for (int j = 0; j < 4; ++j) { s += v[j]; sq += v[j] * v[j]; }
    }
    rs[t] = s; rq[t] = sq;
    __syncthreads();
    for (int off = 128; off > 0; off >>= 1) {
      if (t < off) { rs[t] += rs[t + off]; rq[t] += rq[t + off]; }
      __syncthreads();
    }
    if (t == 0) {
      float mean = rs[0] * (1.f / 4096.f);
      float var = rq[0] * (1.f / 4096.f) - mean * mean;   // biased, torch BN1d
      float rstd = rsqrtf(var + 1e-5f);
      float sc = gg[n] * rstd;
      bc[0] = sc;
      bc[1] = bb[n] - mean * sc;
    }
    __syncthreads();
    float sc = bc[0], sh = bc[1];
#pragma unroll
    for (int i = 0; i < 4; ++i) {
      int b = bq + i * 8;
      f32x4 v = *(const f32x4*)&sm[b * 128 + o4 * 4];
      bf16x4 o;
#pragma unroll
      for (int j = 0; j < 4; ++j) {
        float x = v[j] * sc + sh;
        o[j] = (__bf16)(x > 0.f ? x : 0.f);
      }
      *(bf16x4*)(hb + ((long)b * NNODE + n) * HIDD + o4 * 4) = o;
    }
  }
}

// ---------------- cooperative mega-kernel ----------------
__global__ __launch_bounds__(256, 4) void k_mega(Params P) {
  cg::grid_group grid = cg::this_grid();
  __shared__ __align__(16) char smem[SMEM_BYTES];
  int bid = blockIdx.x, t = threadIdx.x, nbl = gridDim.x;

  pack_phase(P.adj, P.bm, P.degp, bid, t, nbl);
  prep_phase(P, bid, t, nbl);
  grid.sync();

  // layer 0 (K=64, fp32 input x)
  gemm_phase<64, true>(smem, P.x, P.wp + WP_S0, P.bself[0], P.wp + WP_E0,
                       P.bedge[0], P.degp, P.hs, P.mmp, 2560, bid, t, nbl);
  grid.sync();
  spmm_phase(smem, P.bm, P.mmp, P.part, bid, t, nbl);
  grid.sync();
  bnstat_phase<true>(smem, P.hs, P.part, P.bng[0], P.bnb[0], P.hb0, bid, t, nbl);
  grid.sync();

  // layer 1 (K=128)
  gemm_phase<128, false>(smem, P.hb0, P.wp + WP_S1, P.bself[1], P.wp + WP_E1,
                         P.bedge[1], P.degp, P.hs, P.mmp, 2560, bid, t, nbl);
  grid.sync();
  spmm_phase(smem, P.bm, P.mmp, P.part, bid, t, nbl);
  grid.sync();
  bnstat_phase<true>(smem, P.hs, P.part, P.bng[1], P.bnb[1], P.hb1, bid, t, nbl);
  grid.sync();

  // layer 2 (K=128)
  gemm_phase<128, false>(smem, P.hb1, P.wp + WP_S2, P.bself[2], P.wp + WP_E2,
                         P.bedge[2], P.degp, P.hs, P.mmp, 2560, bid, t, nbl);
  grid.sync();
  spmm_phase(smem, P.bm, P.mmp, P.part, bid, t, nbl);
  grid.sync();
  bnstat_phase<true>(smem, P.hs, P.part, P.bng[2], P.bnb[2], P.hb0, bid, t, nbl);
  grid.sync();

  // head: w1 -> BN -> relu -> w2
  gemm_phase<128, false>(smem, P.hb0, P.wp + WP_W1, P.b1, nullptr,
                         nullptr, P.degp, P.hs, nullptr, 512, bid, t, nbl);
  grid.sync();
  bnstat_phase<false>(smem, P.hs, nullptr, P.bnfg, P.bnfb, P.hb1, bid, t, nbl);
  grid.sync();
  gemm_phase<128, false>(smem, P.hb1, P.wp + WP_W2, P.b2, nullptr,
                         nullptr, P.degp, P.out, nullptr, 512, bid, t, nbl);
}

// ---------------- fallback per-phase kernels (r7-equivalent path) ----------------
__global__ __launch_bounds__(256) void g_packprep(Params P) {
  pack_phase(P.adj, P.bm, P.degp, blockIdx.x, threadIdx.x, gridDim.x);
  prep_phase(P, blockIdx.x, threadIdx.x, gridDim.x);
}
template <int K, bool F32IN>
__global__ __launch_bounds__(256) void g_gemm(const void* hv, const __bf16* wps,
                                              const float* bs, const __bf16* wpe,
                                              const float* be, const float* degp,
                                              float* outF, __bf16* mmp, int ntiles) {
  __shared__ __align__(16) char smem[64 * (K + 8) * 2 + K * 64 * 2];
  gemm_phase<K, F32IN>(smem, hv, wps, bs, wpe, be, degp, outF, mmp, ntiles,
                       blockIdx.x, threadIdx.x, gridDim.x);
}
__global__ __launch_bounds__(256) void g_spmm(const uint32_t* bm, const __bf16* mmp,
                                              float* part) {
  __shared__ __align__(16) char smem[8192];
  spmm_phase(smem, bm, mmp, part, blockIdx.x, threadIdx.x, gridDim.x);
}
template <bool HASP>
__global__ __launch_bounds__(256) void g_bnstat(const float* hs, const float* part,
                                                const float* gg, const float* bb,
                                                __bf16* hb) {
  __shared__ __align__(16) char smem[18448];
  bnstat_phase<HASP>(smem, hs, part, gg, bb, hb, blockIdx.x, threadIdx.x, gridDim.x);
}

extern "C" void kernel_launch(void* const* d_in, const int* in_sizes, int n_in,
                              void* d_out, int out_size, void* d_ws, size_t ws_size,
                              hipStream_t stream) {
  (void)in_sizes; (void)n_in; (void)out_size; (void)ws_size;
  Params P;
  P.x   = (const float*)d_in[0];
  P.adj = (const float*)d_in[1];
  for (int l = 0; l < 3; ++l) {
    P.wself[l] = (const float*)d_in[2 + 6 * l];
    P.bself[l] = (const float*)d_in[3 + 6 * l];
    P.wedge[l] = (const float*)d_in[4 + 6 * l];
    P.bedge[l] = (const float*)d_in[5 + 6 * l];
    P.bng[l]   = (const float*)d_in[6 + 6 * l];
    P.bnb[l]   = (const float*)d_in[7 + 6 * l];
  }
  P.w1   = (const float*)d_in[20];
  P.b1   = (const float*)d_in[21];
  P.bnfg = (const float*)d_in[22];
  P.bnfb = (const float*)d_in[23];
  P.w2   = (const float*)d_in[24];
  P.b2   = (const float*)d_in[25];

  char* ws = (char*)d_ws;
  P.mmp  = (__bf16*)ws;                  // 16,777,216
  P.hs   = (float*)(ws + 16777216);      //  8,388,608
  P.part = (float*)(ws + 25165824);      // 33,554,432 (4 x 8 MB)
  P.hb0  = (__bf16*)(ws + 58720256);     //  4,194,304
  P.hb1  = (__bf16*)(ws + 62914560);     //  4,194,304
  P.bm   = (uint32_t*)(ws + 67108864);   //  4,194,304
  P.degp = (float*)(ws + 71303168);      //    262,144
  P.wp   = (__bf16*)(ws + 71565312);     //    475,136 -> ~72.0 MB total
  P.out  = (float*)d_out;

  // adaptive cooperative grid: same arithmetic the launch validator uses
  int dev = 0;
  hipGetDevice(&dev);
  int ncu = 256;
  hipDeviceGetAttribute(&ncu, hipDeviceAttributeMultiprocessorCount, dev);
  int coop = 0;
  hipDeviceGetAttribute(&coop, hipDeviceAttributeCooperativeLaunch, dev);
  int nb = 0;
  hipOccupancyMaxActiveBlocksPerMultiprocessor(&nb, k_mega, 256, 0);

  hipError_t err = hipErrorUnknown;
  if (coop && nb >= 1) {
    long grid = (long)nb * ncu;
    if (grid > 1024) grid = 1024;
    void* args[] = {(void*)&P};
    err = hipLaunchCooperativeKernel((const void*)k_mega, dim3((uint32_t)grid),
                                     dim3(256), args, 0, stream);
  }
  if (err != hipSuccess) {
    // fallback: r7-equivalent multi-kernel path (proven correct/371us)
    g_packprep<<<1024, 256, 0, stream>>>(P);
    // layer 0
    g_gemm<64, true><<<1024, 256, 0, stream>>>(P.x, P.wp + WP_S0, P.bself[0],
                                               P.wp + WP_E0, P.bedge[0], P.degp,
                                               P.hs, P.mmp, 2560);
    g_spmm<<<1024, 256, 0, stream>>>(P.bm, P.mmp, P.part);
    g_bnstat<true><<<512, 256, 0, stream>>>(P.hs, P.part, P.bng[0], P.bnb[0], P.hb0);
    // layer 1
    g_gemm<128, false><<<1024, 256, 0, stream>>>(P.hb0, P.wp + WP_S1, P.bself[1],
                                                 P.wp + WP_E1, P.bedge[1], P.degp,
                                                 P.hs, P.mmp, 2560);
    g_spmm<<<1024, 256, 0, stream>>>(P.bm, P.mmp, P.part);
    g_bnstat<true><<<512, 256, 0, stream>>>(P.hs, P.part, P.bng[1], P.bnb[1], P.hb1);
    // layer 2
    g_gemm<128, false><<<1024, 256, 0, stream>>>(P.hb1, P.wp + WP_S2, P.bself[2],
                                                 P.wp + WP_E2, P.bedge[2], P.degp,
                                                 P.hs, P.mmp, 2560);
    g_spmm<<<1024, 256, 0, stream>>>(P.bm, P.mmp, P.part);
    g_bnstat<true><<<512, 256, 0, stream>>>(P.hs, P.part, P.bng[2], P.bnb[2], P.hb0);
    // head
    g_gemm<128, false><<<512, 256, 0, stream>>>(P.hb0, P.wp + WP_W1, P.b1,
                                                nullptr, nullptr, P.degp,
                                                P.hs, nullptr, 512);
    g_bnstat<false><<<512, 256, 0, stream>>>(P.hs, nullptr, P.bnfg, P.bnfb, P.hb1);
    g_gemm<128, false><<<512, 256, 0, stream>>>(P.hb1, P.wp + WP_W2, P.b2,
                                                nullptr, nullptr, P.degp,
                                                P.out, nullptr, 512);
  }
}

// Round 10
// 367.692 us; speedup vs baseline: 3.1116x; 3.1116x over previous
//
#include <hip/hip_runtime.h>
#include <stdint.h>

// RGCN round 10: back to multi-kernel (r9 post-mortem: grid.sync ~100us each
// on gfx950 -> coop mega-kernel 3x slower; true HBM floor ~71us, multi-kernel
// path is boundary/latency-bound). Bodies are the r9-coop-PROVEN phase
// functions (absmax 0.03125 in r9's passing run): pack+prep fused, inv folded
// into edge-gemm epilogue. 13 launches (was 15). One novelty: part buffer in
// bf16 (halves spmm-write + bnstat-read bytes; error budget ~0.4% rel on
// ~O(0.1) partials, absmax headroom 0.031 -> 0.084).

typedef float  f32x4  __attribute__((ext_vector_type(4)));
typedef __bf16 bf16x8 __attribute__((ext_vector_type(8)));
typedef __bf16 bf16x4 __attribute__((ext_vector_type(4)));
typedef unsigned short ushort8v __attribute__((ext_vector_type(8)));
typedef uint32_t uint4v __attribute__((ext_vector_type(4)));

#define MBATCH 32
#define ETYPES 4
#define NNODE  512
#define HIDD   128

#define GLB(p) (const __attribute__((address_space(1))) uint32_t*)(p)
#define LDSp(p) (__attribute__((address_space(3))) uint32_t*)(p)

// packed-weight pool offsets (elements)
#define WP_S0 0
#define WP_E0 8192
#define WP_S1 40960
#define WP_E1 57344
#define WP_S2 122880
#define WP_E2 139264
#define WP_W1 204800
#define WP_W2 221184

struct Params {
  const float* x;
  const float* adj;
  const float* wself[3]; const float* bself[3];
  const float* wedge[3]; const float* bedge[3];
  const float* bng[3];   const float* bnb[3];
  const float* w1; const float* b1;
  const float* bnfg; const float* bnfb;
  const float* w2; const float* b2;
  __bf16* mmp; float* hs; __bf16* part;
  __bf16* hb0; __bf16* hb1;
  uint32_t* bm; float* degp; __bf16* wp;
  float* out;
};

// ---------------- phase: pack (r9-proven body) ----------------
__device__ void pack_phase(const float* __restrict__ adj, uint32_t* __restrict__ bm,
                           float* __restrict__ degp, int bid, int t, int nbl) {
  int wave = t >> 6, lane = t & 63;
  for (int rg = bid; rg < 16384; rg += nbl) {
    int r = rg * 4 + wave;                  // 65536 rows (b,e,n)
    int b = r >> 11, e = (r >> 9) & 3, n = r & 511;
    const float* row = adj + (long)r * 512;
    uint32_t myw = 0;
#pragma unroll
    for (int i = 0; i < 8; ++i) {
      uint64_t bal = __ballot(row[i * 64 + lane] != 0.f);
      uint32_t lo = (uint32_t)bal, hi = (uint32_t)(bal >> 32);
      if ((lane >> 1) == i) myw = (lane & 1) ? hi : lo;
    }
    if (lane == (n >> 5)) myw &= ~(1u << (n & 31));   // zero diagonal
    int pc = (lane < 16) ? __popc(myw) : 0;
    pc += __shfl_down(pc, 8);
    pc += __shfl_down(pc, 4);
    pc += __shfl_down(pc, 2);
    pc += __shfl_down(pc, 1);
    if (lane < 16) bm[(long)r * 16 + lane] = myw;
    if (lane == 0) degp[e * 16384 + b * 512 + n] = (float)pc;
  }
}

// ---------------- phase: prep (r9-proven body) ----------------
__device__ void prep_phase(const Params& P, int bid, int t, int nbl) {
  const float* Ws[8] = {P.wself[0], P.wedge[0], P.wself[1], P.wedge[1],
                        P.wself[2], P.wedge[2], P.w1, P.w2};
  const int Kt[8]  = {64, 64, 128, 128, 128, 128, 128, 128};
  const int NB[8]  = {2, 8, 2, 8, 2, 8, 2, 2};
  const int OFF[8] = {WP_S0, WP_E0, WP_S1, WP_E1, WP_S2, WP_E2, WP_W1, WP_W2};
#pragma unroll
  for (int wid = 0; wid < 8; ++wid) {
    int K = Kt[wid], nblk = NB[wid];
    int tot = K * nblk * 64;
    for (int gid = bid * 256 + t; gid < tot; gid += nbl * 256) {
      int c = gid & 63;
      int k = (gid >> 6) % K;
      int blk = (gid >> 6) / K;
      int edge = (nblk == 8);
      int WS = edge ? 512 : 128;
      int col = edge ? (((blk & 1) * 64 + c) * 4 + (blk >> 1)) : (blk * 64 + c);
      P.wp[OFF[wid] + (long)blk * K * 64 + (k >> 3) * 512 + c * 8 + (k & 7)] =
          (__bf16)Ws[wid][k * WS + col];
    }
  }
}

// ---------------- phase: gemm (r9-proven body; iv from degp inline) ----------------
template <int K, bool F32IN>
__device__ void gemm_phase(char* smem, const void* __restrict__ hv,
                           const __bf16* __restrict__ wp_self,
                           const float* __restrict__ bias_self,
                           const __bf16* __restrict__ wp_edge,
                           const float* __restrict__ bias_edge,
                           const float* __restrict__ degp,
                           float* __restrict__ outF, __bf16* __restrict__ mmp,
                           int ntiles, int bid, int t, int nbl) {
  __bf16 (*Hl)[K + 8] = (__bf16(*)[K + 8])smem;
  __bf16* Wl = (__bf16*)(smem + 64 * (K + 8) * 2);   // k-packed [K/8][64][8]
  int wave = t >> 6, lane = t & 63, l15 = lane & 15, q = lane >> 4;
  for (int tile = bid; tile < ntiles; tile += nbl) {
    __syncthreads();                     // smem free from prev tile
    int g0 = (tile & 255) * 64;
    int by = tile >> 8;
    bool edge = by >= 2;
    // stage W: contiguous K*128-byte copy via global_load_lds
    {
      const __bf16* wblk = edge ? (wp_edge + (long)(by - 2) * K * 64)
                                : (wp_self + (long)by * K * 64);
      const char* g = (const char*)wblk;
#pragma unroll
      for (int i = 0; i < K / 32; ++i) {
        __builtin_amdgcn_global_load_lds(GLB(g + i * 4096 + wave * 1024 + lane * 16),
                                         LDSp((char*)Wl + i * 4096 + wave * 1024),
                                         16, 0, 0);
      }
    }
    // stage H (coalesced, padded rows)
    for (int idx = t; idx < 64 * (K / 8); idx += 256) {
      int r = idx / (K / 8), ch = idx % (K / 8);
      if (F32IN) {
        const float* xf = (const float*)hv;
        f32x4 a = *(const f32x4*)(xf + (long)(g0 + r) * K + ch * 8);
        f32x4 bq = *(const f32x4*)(xf + (long)(g0 + r) * K + ch * 8 + 4);
        bf16x8 o;
#pragma unroll
        for (int j = 0; j < 4; ++j) { o[j] = (__bf16)a[j]; o[4 + j] = (__bf16)bq[j]; }
        *(bf16x8*)&Hl[r][ch * 8] = o;
      } else {
        const __bf16* hb = (const __bf16*)hv;
        *(bf16x8*)&Hl[r][ch * 8] = *(const bf16x8*)(hb + (long)(g0 + r) * K + ch * 8);
      }
    }
    __syncthreads();
    f32x4 acc[4] = {};
#pragma unroll
    for (int kk = 0; kk < K / 32; ++kk) {
      bf16x8 af = *(const bf16x8*)&Hl[wave * 16 + l15][kk * 32 + q * 8];
#pragma unroll
      for (int c = 0; c < 4; ++c) {
        bf16x8 bfr = *(const bf16x8*)&Wl[((kk * 4 + q) * 64 + c * 16 + l15) * 8];
        acc[c] = __builtin_amdgcn_mfma_f32_16x16x32_bf16(af, bfr, acc[c], 0, 0, 0);
      }
    }
    // D: row = q*4+i (within wave's 16-row tile), col = c*16+l15
    if (!edge) {
      int c0 = by * 64;
#pragma unroll
      for (int c = 0; c < 4; ++c) {
        float bc = bias_self[c0 + c * 16 + l15];
#pragma unroll
        for (int i = 0; i < 4; ++i) {
          int g = g0 + wave * 16 + q * 4 + i;
          outF[(long)g * HIDD + c0 + c * 16 + l15] = acc[c][i] + bc;
        }
      }
    } else {
      int blk = by - 2;
      int e = blk >> 1, o0 = (blk & 1) * 64;
      float iv[4];
#pragma unroll
      for (int i = 0; i < 4; ++i) {
        int gg = g0 + wave * 16 + q * 4 + i;
        float d = degp[gg] + degp[16384 + gg] + degp[32768 + gg] + degp[49152 + gg];
        iv[i] = d > 0.f ? 1.f / d : 0.f;       // bit-identical to k_inv
      }
      int b4e  = (g0 >> 9) * 4 + e;
      int octg = ((g0 & 511) >> 3) + wave * 2 + (q >> 1);
      int j0   = (q & 1) * 4;
#pragma unroll
      for (int c = 0; c < 4; ++c) {
        int o = o0 + c * 16 + l15;
        float bc = bias_edge[o * 4 + e];
        bf16x4 v4;
#pragma unroll
        for (int i = 0; i < 4; ++i) v4[i] = (__bf16)((acc[c][i] + bc) * iv[i]);
        *(bf16x4*)(mmp + ((long)(b4e * 64 + octg) * HIDD + o) * 8 + j0) = v4;
      }
    }
  }
}

// ---------------- phase: spmm (r9-proven body; part now bf16) ----------------
__device__ void spmm_phase(char* smem, const uint32_t* __restrict__ bm,
                           const __bf16* __restrict__ mmp,
                           __bf16* __restrict__ part, int bid, int t, int nbl) {
  __bf16* Bl = (__bf16*)smem;           // [oct(8)][o_local(64)][j(8)] = 8 KB
  int wave = t >> 6, lane = t & 63, l15 = lane & 15, q = lane >> 4;
  for (int tl = bid; tl < 1024; tl += nbl) {
    int tile = tl >> 7;                 // 0..7 = nt*2 + oc
    int eb   = tl & 127;                // e*32 + b
    int e = eb >> 5, b = eb & 31;
    int nt = tile >> 1, oc = tile & 1;
    int n0 = nt * 128, o0 = oc * 64;

    const uint32_t* bmr = bm + ((long)((b * 4 + e) * 512 + n0 + wave * 32 + l15)) * 16;
    uint32_t rm0[16], rm1[16];
#pragma unroll
    for (int i = 0; i < 4; ++i) {
      uint4v v0 = *(const uint4v*)(bmr + i * 4);
      uint4v v1 = *(const uint4v*)(bmr + 256 + i * 4);   // +16 rows * 16 words
      rm0[i * 4 + 0] = v0.x; rm0[i * 4 + 1] = v0.y; rm0[i * 4 + 2] = v0.z; rm0[i * 4 + 3] = v0.w;
      rm1[i * 4 + 0] = v1.x; rm1[i * 4 + 1] = v1.y; rm1[i * 4 + 2] = v1.z; rm1[i * 4 + 3] = v1.w;
    }

    f32x4 acc0[4] = {}, acc1[4] = {};
#pragma unroll 1
    for (int mc = 0; mc < 8; ++mc) {
      __syncthreads();   // Bl free from previous iter / tile
#pragma unroll
      for (int i = 0; i < 2; ++i) {
        int oct = wave * 2 + i;
        const char* g = (const char*)mmp +
            ((long)(b * 4 + e) * 65536 + mc * 8192 + oct * 1024 + o0 * 8) * 2;
        __builtin_amdgcn_global_load_lds(GLB(g + lane * 16),
                                         LDSp((char*)Bl + oct * 1024),
                                         16, 0, 0);
      }
      __syncthreads();   // loads drained
#pragma unroll
      for (int kk = 0; kk < 2; ++kk) {
        uint32_t bits0 = (rm0[mc * 2 + kk] >> (q * 8)) & 0xffu;
        uint32_t bits1 = (rm1[mc * 2 + kk] >> (q * 8)) & 0xffu;
        ushort8v a0, a1;
#pragma unroll
        for (int j = 0; j < 8; ++j) {
          a0[j] = (bits0 >> j & 1u) ? (unsigned short)0x3F80 : (unsigned short)0;
          a1[j] = (bits1 >> j & 1u) ? (unsigned short)0x3F80 : (unsigned short)0;
        }
        union { ushort8v u; bf16x8 v; } c0, c1; c0.u = a0; c1.u = a1;
#pragma unroll
        for (int c = 0; c < 4; ++c) {
          bf16x8 bfr = *(const bf16x8*)&Bl[((kk * 4 + q) * 64 + c * 16 + l15) * 8];
          acc0[c] = __builtin_amdgcn_mfma_f32_16x16x32_bf16(c0.v, bfr, acc0[c], 0, 0, 0);
          acc1[c] = __builtin_amdgcn_mfma_f32_16x16x32_bf16(c1.v, bfr, acc1[c], 0, 0, 0);
        }
      }
    }
    __bf16* dst = part + (long)(e * 32 + b) * NNODE * HIDD;
#pragma unroll
    for (int c = 0; c < 4; ++c) {
#pragma unroll
      for (int i = 0; i < 4; ++i) {
        int n = n0 + wave * 32 + q * 4 + i;
        int o = o0 + c * 16 + l15;
        dst[(long)n * HIDD + o] = (__bf16)acc0[c][i];
        dst[(long)(n + 16) * HIDD + o] = (__bf16)acc1[c][i];
      }
    }
  }
}

// ---------------- phase: bnstat (r9-proven body; part reads bf16) ----------------
template <bool HASP>
__device__ void bnstat_phase(char* smem, const float* __restrict__ hs,
                             const __bf16* __restrict__ part,
                             const float* __restrict__ gg,
                             const float* __restrict__ bb,
                             __bf16* __restrict__ hb, int bid, int t, int nbl) {
  float* sm = (float*)smem;             // 4096 floats
  float* rs = (float*)(smem + 16384);   // 256
  float* rq = (float*)(smem + 17408);   // 256
  float* bc = (float*)(smem + 18432);   // 2
  int o4 = t & 31, bq = t >> 5;
  for (int n = bid; n < 512; n += nbl) {
    __syncthreads();                    // smem free from previous n
    float s = 0.f, sq = 0.f;
#pragma unroll
    for (int i = 0; i < 4; ++i) {
      int b = bq + i * 8;
      long base = ((long)b * NNODE + n) * HIDD + o4 * 4;
      f32x4 v = *(const f32x4*)(hs + base);
      if (HASP) {
#pragma unroll
        for (int e = 0; e < 4; ++e) {
          bf16x4 pv = *(const bf16x4*)(part + ((long)(e * 32 + b) * NNODE + n) * HIDD + o4 * 4);
#pragma unroll
          for (int j = 0; j < 4; ++j) v[j] += (float)pv[j];
        }
      }
      *(f32x4*)&sm[b * 128 + o4 * 4] = v;
#pragma unroll
      for (int j = 0; j < 4; ++j) { s += v[j]; sq += v[j] * v[j]; }
    }
    rs[t] = s; rq[t] = sq;
    __syncthreads();
    for (int off = 128; off > 0; off >>= 1) {
      if (t < off) { rs[t] += rs[t + off]; rq[t] += rq[t + off]; }
      __syncthreads();
    }
    if (t == 0) {
      float mean = rs[0] * (1.f / 4096.f);
      float var = rq[0] * (1.f / 4096.f) - mean * mean;   // biased, torch BN1d
      float rstd = rsqrtf(var + 1e-5f);
      float sc = gg[n] * rstd;
      bc[0] = sc;
      bc[1] = bb[n] - mean * sc;
    }
    __syncthreads();
    float sc = bc[0], sh = bc[1];
#pragma unroll
    for (int i = 0; i < 4; ++i) {
      int b = bq + i * 8;
      f32x4 v = *(const f32x4*)&sm[b * 128 + o4 * 4];
      bf16x4 o;
#pragma unroll
      for (int j = 0; j < 4; ++j) {
        float x = v[j] * sc + sh;
        o[j] = (__bf16)(x > 0.f ? x : 0.f);
      }
      *(bf16x4*)(hb + ((long)b * NNODE + n) * HIDD + o4 * 4) = o;
    }
  }
}

// ---------------- kernels ----------------
__global__ __launch_bounds__(256) void g_packprep(Params P) {
  pack_phase(P.adj, P.bm, P.degp, blockIdx.x, threadIdx.x, gridDim.x);
  prep_phase(P, blockIdx.x, threadIdx.x, gridDim.x);
}
template <int K, bool F32IN>
__global__ __launch_bounds__(256) void g_gemm(const void* hv, const __bf16* wps,
                                              const float* bs, const __bf16* wpe,
                                              const float* be, const float* degp,
                                              float* outF, __bf16* mmp, int ntiles) {
  __shared__ __align__(16) char smem[64 * (K + 8) * 2 + K * 64 * 2];
  gemm_phase<K, F32IN>(smem, hv, wps, bs, wpe, be, degp, outF, mmp, ntiles,
                       blockIdx.x, threadIdx.x, gridDim.x);
}
__global__ __launch_bounds__(256) void g_spmm(const uint32_t* bm, const __bf16* mmp,
                                              __bf16* part) {
  __shared__ __align__(16) char smem[8192];
  spmm_phase(smem, bm, mmp, part, blockIdx.x, threadIdx.x, gridDim.x);
}
template <bool HASP>
__global__ __launch_bounds__(256) void g_bnstat(const float* hs, const __bf16* part,
                                                const float* gg, const float* bb,
                                                __bf16* hb) {
  __shared__ __align__(16) char smem[18448];
  bnstat_phase<HASP>(smem, hs, part, gg, bb, hb, blockIdx.x, threadIdx.x, gridDim.x);
}

extern "C" void kernel_launch(void* const* d_in, const int* in_sizes, int n_in,
                              void* d_out, int out_size, void* d_ws, size_t ws_size,
                              hipStream_t stream) {
  (void)in_sizes; (void)n_in; (void)out_size; (void)ws_size;
  Params P;
  P.x   = (const float*)d_in[0];
  P.adj = (const float*)d_in[1];
  for (int l = 0; l < 3; ++l) {
    P.wself[l] = (const float*)d_in[2 + 6 * l];
    P.bself[l] = (const float*)d_in[3 + 6 * l];
    P.wedge[l] = (const float*)d_in[4 + 6 * l];
    P.bedge[l] = (const float*)d_in[5 + 6 * l];
    P.bng[l]   = (const float*)d_in[6 + 6 * l];
    P.bnb[l]   = (const float*)d_in[7 + 6 * l];
  }
  P.w1   = (const float*)d_in[20];
  P.b1   = (const float*)d_in[21];
  P.bnfg = (const float*)d_in[22];
  P.bnfb = (const float*)d_in[23];
  P.w2   = (const float*)d_in[24];
  P.b2   = (const float*)d_in[25];

  char* ws = (char*)d_ws;
  P.mmp  = (__bf16*)ws;                  // 16,777,216
  P.hs   = (float*)(ws + 16777216);      //  8,388,608
  P.part = (__bf16*)(ws + 25165824);     // 16,777,216 (bf16 now)
  P.hb0  = (__bf16*)(ws + 41943040);     //  4,194,304
  P.hb1  = (__bf16*)(ws + 46137344);     //  4,194,304
  P.bm   = (uint32_t*)(ws + 50331648);   //  4,194,304
  P.degp = (float*)(ws + 54525952);      //    262,144
  P.wp   = (__bf16*)(ws + 54788096);     //    475,136 -> ~55.3 MB total
  P.out  = (float*)d_out;

  g_packprep<<<16384, 256, 0, stream>>>(P);

  // layer 0 (K=64, fp32 input x)
  g_gemm<64, true><<<2560, 256, 0, stream>>>(P.x, P.wp + WP_S0, P.bself[0],
                                             P.wp + WP_E0, P.bedge[0], P.degp,
                                             P.hs, P.mmp, 2560);
  g_spmm<<<1024, 256, 0, stream>>>(P.bm, P.mmp, P.part);
  g_bnstat<true><<<512, 256, 0, stream>>>(P.hs, P.part, P.bng[0], P.bnb[0], P.hb0);

  // layer 1 (K=128)
  g_gemm<128, false><<<2560, 256, 0, stream>>>(P.hb0, P.wp + WP_S1, P.bself[1],
                                               P.wp + WP_E1, P.bedge[1], P.degp,
                                               P.hs, P.mmp, 2560);
  g_spmm<<<1024, 256, 0, stream>>>(P.bm, P.mmp, P.part);
  g_bnstat<true><<<512, 256, 0, stream>>>(P.hs, P.part, P.bng[1], P.bnb[1], P.hb1);

  // layer 2 (K=128)
  g_gemm<128, false><<<2560, 256, 0, stream>>>(P.hb1, P.wp + WP_S2, P.bself[2],
                                               P.wp + WP_E2, P.bedge[2], P.degp,
                                               P.hs, P.mmp, 2560);
  g_spmm<<<1024, 256, 0, stream>>>(P.bm, P.mmp, P.part);
  g_bnstat<true><<<512, 256, 0, stream>>>(P.hs, P.part, P.bng[2], P.bnb[2], P.hb0);

  // head: w1 -> BN -> relu -> w2
  g_gemm<128, false><<<512, 256, 0, stream>>>(P.hb0, P.wp + WP_W1, P.b1,
                                              nullptr, nullptr, P.degp,
                                              P.hs, nullptr, 512);
  g_bnstat<false><<<512, 256, 0, stream>>>(P.hs, nullptr, P.bnfg, P.bnfb, P.hb1);
  g_gemm<128, false><<<512, 256, 0, stream>>>(P.hb1, P.wp + WP_W2, P.b2,
                                              nullptr, nullptr, P.degp,
                                              P.out, nullptr, 512);
}